// Round 4
// baseline (135.129 us; speedup 1.0000x reference)
//
#include <hip/hip_runtime.h>
#include <math.h>

#define S_PNTS 8
#define NUM_POINTS 2
#define NB 8
#define NQ 500
#define NC 256
#define S_SCALE 0.077f
#define QPB 4                 // queries per block (finer granularity: 1000 blocks)
#define ROWS (QPB * S_PNTS)   // 32 M-rows per block
#define APAD 264              // LDS leading dim bf16: 528 B -> 16B-aligned rows, 2-way bank alias only (free)

typedef __bf16 bf16x8 __attribute__((ext_vector_type(8)));
typedef __bf16 bf16x4 __attribute__((ext_vector_type(4)));
typedef float  f32x4  __attribute__((ext_vector_type(4)));

__device__ __forceinline__ float fast_tanh(float x) {
    float xc = fminf(fmaxf(x, -14.0f), 14.0f);
    float t  = __builtin_amdgcn_exp2f(xc * 2.88539008178f);
    return 1.0f - 2.0f * __builtin_amdgcn_rcpf(t + 1.0f);
}

// 1000 blocks x 512 threads / 8 waves. Each wave owns a 32-col N-slice of the
// layer-1 GEMM (bfrag 8x2=64 VGPR, acc 2x2=16). W1 bfrag loads are issued
// BEFORE the first barrier (no dependencies) so their L2 latency drains under
// the phase-1 prologue; the bilinear gather then owns the vmem queue.
__global__ __launch_bounds__(512, 4) void decoder_kernel(
    const float* __restrict__ ref_polys,   // (B, Q, 8)
    const int*   __restrict__ ref_levels,  // (B, Q)
    const float* __restrict__ memory,      // (B, 8500, 256)
    const float* __restrict__ W1,          // (256, 256) [k][n] fp32
    const float* __restrict__ b1,          // (256,)
    const float* __restrict__ W2,          // (256, 4)
    const float* __restrict__ b2,          // (4,)
    float*       __restrict__ out)         // (B, Q, 16, 2)
{
    const int tid  = threadIdx.x;
    const int w    = tid >> 6;        // 0..7
    const int l    = tid & 63;
    const int lrow = l & 15;
    const int quad = l >> 4;

    __shared__ __bf16 emb_lds[ROWS * APAD];        // 16.9 KB A-tile
    __shared__ __bf16 h_lds[ROWS * APAD];          // 16.9 KB h (separate -> one fewer barrier)
    __shared__ float  b1_lds[NC];
    __shared__ int4   p_idx[ROWS];
    __shared__ float4 p_w[ROWS];
    __shared__ float2 spts_lds[ROWS];

    // ---- phase 1: per-row sampling params (first 32 lanes of wave 0) ----
    if (tid < ROWS) {
        const int r = tid, s = r & 7;
        const int qg = blockIdx.x * QPB + (r >> 3);
        const int b  = qg / NQ;
        const int lvl = ref_levels[qg];
        const int W  = 80 >> lvl;                                    // 80,40,20,10
        const int st = (lvl >= 1) * 6400 + (lvl >= 2) * 1600 + (lvl >= 3) * 400;
        const float* rp = ref_polys + (size_t)qg * 8;
        float lam = (float)s * (1.0f / 7.0f);
        float sx = 2.0f * ((((rp[0] * lam + rp[1]) * lam + rp[2]) * lam + rp[3]) - 0.5f);
        float sy = 2.0f * ((((rp[4] * lam + rp[5]) * lam + rp[6]) * lam + rp[7]) - 0.5f);
        spts_lds[r] = make_float2(sx, sy);
        float gx = (sx + 1.0f) * 0.5f * (float)W - 0.5f;
        float gy = (sy + 1.0f) * 0.5f * (float)W - 0.5f;
        float x0f = floorf(gx), y0f = floorf(gy);
        int   x0 = (int)x0f,    y0 = (int)y0f;
        float wx1 = gx - x0f, wx0 = 1.0f - wx1;
        float wy1 = gy - y0f, wy0 = 1.0f - wy1;
        float xv0 = (x0 >= 0 && x0 < W) ? 1.0f : 0.0f;
        float xv1 = (x0 + 1 >= 0 && x0 + 1 < W) ? 1.0f : 0.0f;
        float yv0 = (y0 >= 0 && y0 < W) ? 1.0f : 0.0f;
        float yv1 = (y0 + 1 >= 0 && y0 + 1 < W) ? 1.0f : 0.0f;
        int xc0 = min(max(x0, 0), W - 1),     xc1 = min(max(x0 + 1, 0), W - 1);
        int yc0 = min(max(y0, 0), W - 1),     yc1 = min(max(y0 + 1, 0), W - 1);
        int base = b * 8500 + st;
        p_idx[r] = make_int4(base + yc0 * W + xc0, base + yc0 * W + xc1,
                             base + yc1 * W + xc0, base + yc1 * W + xc1);
        p_w[r] = make_float4(wy0 * wx0 * yv0 * xv0, wy0 * wx1 * yv0 * xv1,
                             wy1 * wx0 * yv1 * xv0, wy1 * wx1 * yv1 * xv1);
    }

    // ---- phase 0: W1 B-fragments (this wave's 32 cols), fp32 -> bf16 in-register.
    // Issued BEFORE the first barrier: latency hides under phase 1 + barrier.
    // frag[ks][nt] lane layout: n = w*32+nt*16+lrow, k = ks*32+quad*8+e.
    bf16x8 bfrag[8][2];
    {
        const int kbase = quad * 8;
        #pragma unroll
        for (int ks = 0; ks < 8; ++ks) {
            #pragma unroll
            for (int nt = 0; nt < 2; ++nt) {
                const int n = w * 32 + nt * 16 + lrow;
                const float* src = W1 + (ks * 32 + kbase) * NC + n;
                bf16x8 f;
                #pragma unroll
                for (int e = 0; e < 8; ++e)
                    f[e] = (__bf16)src[e * NC];
                bfrag[ks][nt] = f;
            }
        }
    }
    if (tid < NC) b1_lds[tid] = b1[tid];
    const float b2v = b2[lrow & 3];      // tiny, L1-broadcast; needed only in epilogue
    __syncthreads();

    // ---- phase 2: bilinear gather -> emb_lds bf16, float4 loads. 4 iters/thread.
    {
        const int c4  = tid & 63;
        const int rg0 = tid >> 6;       // 0..7
        const float4* m4 = (const float4*)memory;
        #pragma unroll
        for (int i = 0; i < 4; ++i) {
            int r = i * 8 + rg0;
            int4   id = p_idx[r];
            float4 wv = p_w[r];
            float4 v00 = m4[(size_t)id.x * 64 + c4];
            float4 v01 = m4[(size_t)id.y * 64 + c4];
            float4 v10 = m4[(size_t)id.z * 64 + c4];
            float4 v11 = m4[(size_t)id.w * 64 + c4];
            bf16x4 e;
            e[0] = (__bf16)(wv.x * v00.x + wv.y * v01.x + wv.z * v10.x + wv.w * v11.x);
            e[1] = (__bf16)(wv.x * v00.y + wv.y * v01.y + wv.z * v10.y + wv.w * v11.y);
            e[2] = (__bf16)(wv.x * v00.z + wv.y * v01.z + wv.z * v10.z + wv.w * v11.z);
            e[3] = (__bf16)(wv.x * v00.w + wv.y * v01.w + wv.z * v10.w + wv.w * v11.w);
            *(bf16x4*)&emb_lds[r * APAD + c4 * 4] = e;
        }
    }
    __syncthreads();

    // ---- phase 3: layer-1 MFMA, 32 rows x 32 cols per wave ----
    f32x4 acc[2][2] = {};
    #pragma unroll
    for (int ks = 0; ks < 8; ++ks) {
        bf16x8 a[2];
        #pragma unroll
        for (int mt = 0; mt < 2; ++mt)
            a[mt] = *(const bf16x8*)&emb_lds[(mt * 16 + lrow) * APAD + ks * 32 + quad * 8];
        #pragma unroll
        for (int nt = 0; nt < 2; ++nt)
            #pragma unroll
            for (int mt = 0; mt < 2; ++mt)
                acc[mt][nt] = __builtin_amdgcn_mfma_f32_16x16x32_bf16(a[mt], bfrag[ks][nt], acc[mt][nt], 0, 0, 0);
    }

    // ---- phase 3.5: W2 hi/lo bf16 B-fragments, waves 0-1 only (they run phase 5).
    // 4 KB L1/L2-hot table; loads hide under phase-4 tanh VALU.
    bf16x8 w2hi[8], w2lo[8];
    if (w < 2) {
        const int jj = lrow & 3;
        const float zval = (lrow < 4) ? 1.0f : 0.0f;
        #pragma unroll
        for (int ks = 0; ks < 8; ++ks) {
            bf16x8 h8, l8;
            #pragma unroll
            for (int e = 0; e < 8; ++e) {
                float v = W2[(ks * 32 + quad * 8 + e) * 4 + jj] * zval;
                __bf16 hi = (__bf16)v;
                __bf16 lo = (__bf16)(v - (float)hi);
                h8[e] = hi; l8[e] = lo;
            }
            w2hi[ks] = h8; w2lo[ks] = l8;
        }
    }

    // ---- phase 4: h = fast_tanh(acc + b1) -> h_lds (separate buffer, no pre-barrier) ----
    #pragma unroll
    for (int mt = 0; mt < 2; ++mt) {
        #pragma unroll
        for (int nt = 0; nt < 2; ++nt) {
            const int n = w * 32 + nt * 16 + lrow;
            const float bias = b1_lds[n];
            #pragma unroll
            for (int rg = 0; rg < 4; ++rg) {
                const int row = mt * 16 + quad * 4 + rg;
                h_lds[row * APAD + n] = (__bf16)fast_tanh(acc[mt][nt][rg] + bias);
            }
        }
    }
    __syncthreads();

    // ---- phase 5: layer-2 via MFMA on waves 0-1 (16 rows each); others exit.
    // acc2 layout: row = quad*4+rg, col(j) = lrow.
    if (w < 2) {
        f32x4 acc2 = {};
        #pragma unroll
        for (int ks = 0; ks < 8; ++ks) {
            bf16x8 a = *(const bf16x8*)&h_lds[(w * 16 + lrow) * APAD + ks * 32 + quad * 8];
            acc2 = __builtin_amdgcn_mfma_f32_16x16x32_bf16(a, w2lo[ks], acc2, 0, 0, 0);
            acc2 = __builtin_amdgcn_mfma_f32_16x16x32_bf16(a, w2hi[ks], acc2, 0, 0, 0);
        }
        if (lrow < 4) {
            const int j = lrow;
            #pragma unroll
            for (int rg = 0; rg < 4; ++rg) {
                const int r  = w * 16 + quad * 4 + rg;
                const int s  = r & 7;
                const int qg = blockIdx.x * QPB + (r >> 3);
                float o = S_SCALE * fast_tanh(acc2[rg] + b2v);
                float2 sp2 = spts_lds[r];
                float sp = ((j & 1) == 0) ? sp2.x : sp2.y;
                out[(size_t)qg * 32 + s * 4 + j] = o + sp;
            }
        }
    }
}

extern "C" void kernel_launch(void* const* d_in, const int* in_sizes, int n_in,
                              void* d_out, int out_size, void* d_ws, size_t ws_size,
                              hipStream_t stream) {
    const float* ref_polys  = (const float*)d_in[0];
    const int*   ref_levels = (const int*)d_in[1];
    const float* memory     = (const float*)d_in[2];
    const float* W1         = (const float*)d_in[3];
    const float* b1         = (const float*)d_in[4];
    const float* W2         = (const float*)d_in[5];
    const float* b2         = (const float*)d_in[6];
    float* out = (float*)d_out;
    (void)d_ws; (void)ws_size;

    decoder_kernel<<<dim3(NB * NQ / QPB), dim3(512), 0, stream>>>(
        ref_polys, ref_levels, memory, W1, b1, W2, b2, out);
}

// Round 5
// 118.199 us; speedup vs baseline: 1.1432x; 1.1432x over previous
//
#include <hip/hip_runtime.h>
#include <math.h>

#define S_PNTS 8
#define NUM_POINTS 2
#define NB 8
#define NQ 500
#define NC 256
#define S_SCALE 0.077f
#define QPB 8                 // queries per block
#define ROWS (QPB * S_PNTS)   // 64 M-rows per block
#define APAD 264              // LDS leading dim bf16: 528 B -> 16B-aligned rows, 2-way bank alias only (free)

typedef __bf16 bf16x8 __attribute__((ext_vector_type(8)));
typedef __bf16 bf16x4 __attribute__((ext_vector_type(4)));
typedef float  f32x4  __attribute__((ext_vector_type(4)));

__device__ __forceinline__ float fast_tanh(float x) {
    float xc = fminf(fmaxf(x, -14.0f), 14.0f);
    float t  = __builtin_amdgcn_exp2f(xc * 2.88539008178f);
    return 1.0f - 2.0f * __builtin_amdgcn_rcpf(t + 1.0f);
}

// Proven-best configuration (round 3, 119.3 us): 500 blocks x 512 threads /
// 8 waves, each wave owns a 32-col N-slice (bfrag 8x2 = 64 VGPR, acc 4x2 = 32).
// __launch_bounds__(512,4) -> VGPR<=128 -> 16 waves/CU (the VGPR-bound ceiling;
// QPB=4 (1000 blocks) regressed +16 us from doubled per-block fixed costs,
// bfrag-before-gather ordering regressed vs gather-first).
__global__ __launch_bounds__(512, 4) void decoder_kernel(
    const float* __restrict__ ref_polys,   // (B, Q, 8)
    const int*   __restrict__ ref_levels,  // (B, Q)
    const float* __restrict__ memory,      // (B, 8500, 256)
    const float* __restrict__ W1,          // (256, 256) [k][n] fp32
    const float* __restrict__ b1,          // (256,)
    const float* __restrict__ W2,          // (256, 4)
    const float* __restrict__ b2,          // (4,)
    float*       __restrict__ out)         // (B, Q, 16, 2)
{
    const int tid  = threadIdx.x;
    const int w    = tid >> 6;        // 0..7
    const int l    = tid & 63;
    const int lrow = l & 15;
    const int quad = l >> 4;

    __shared__ __bf16 emb_lds[ROWS * APAD];        // 33.8 KB A-tile
    __shared__ __bf16 h_lds[ROWS * APAD];          // 33.8 KB h (separate -> one fewer barrier)
    __shared__ float  b1_lds[NC];
    __shared__ int4   p_idx[ROWS];
    __shared__ float4 p_w[ROWS];
    __shared__ float2 spts_lds[ROWS];

    // ---- phase 1: per-row sampling params (one wave) ----
    if (tid < ROWS) {
        const int r = tid, s = r & 7;
        const int qg = blockIdx.x * QPB + (r >> 3);
        const int b  = qg / NQ;
        const int lvl = ref_levels[qg];
        const int W  = 80 >> lvl;                                    // 80,40,20,10
        const int st = (lvl >= 1) * 6400 + (lvl >= 2) * 1600 + (lvl >= 3) * 400;
        const float* rp = ref_polys + (size_t)qg * 8;
        float lam = (float)s * (1.0f / 7.0f);
        float sx = 2.0f * ((((rp[0] * lam + rp[1]) * lam + rp[2]) * lam + rp[3]) - 0.5f);
        float sy = 2.0f * ((((rp[4] * lam + rp[5]) * lam + rp[6]) * lam + rp[7]) - 0.5f);
        spts_lds[r] = make_float2(sx, sy);
        float gx = (sx + 1.0f) * 0.5f * (float)W - 0.5f;
        float gy = (sy + 1.0f) * 0.5f * (float)W - 0.5f;
        float x0f = floorf(gx), y0f = floorf(gy);
        int   x0 = (int)x0f,    y0 = (int)y0f;
        float wx1 = gx - x0f, wx0 = 1.0f - wx1;
        float wy1 = gy - y0f, wy0 = 1.0f - wy1;
        float xv0 = (x0 >= 0 && x0 < W) ? 1.0f : 0.0f;
        float xv1 = (x0 + 1 >= 0 && x0 + 1 < W) ? 1.0f : 0.0f;
        float yv0 = (y0 >= 0 && y0 < W) ? 1.0f : 0.0f;
        float yv1 = (y0 + 1 >= 0 && y0 + 1 < W) ? 1.0f : 0.0f;
        int xc0 = min(max(x0, 0), W - 1),     xc1 = min(max(x0 + 1, 0), W - 1);
        int yc0 = min(max(y0, 0), W - 1),     yc1 = min(max(y0 + 1, 0), W - 1);
        int base = b * 8500 + st;
        p_idx[r] = make_int4(base + yc0 * W + xc0, base + yc0 * W + xc1,
                             base + yc1 * W + xc0, base + yc1 * W + xc1);
        p_w[r] = make_float4(wy0 * wx0 * yv0 * xv0, wy0 * wx1 * yv0 * xv1,
                             wy1 * wx0 * yv1 * xv0, wy1 * wx1 * yv1 * xv1);
    }
    if (tid < NC) b1_lds[tid] = b1[tid];
    const float b2v = b2[lrow & 3];      // tiny, L1-broadcast; needed only in epilogue
    __syncthreads();

    // ---- phase 2: bilinear gather -> emb_lds bf16, float4 loads ----
    // Issued FIRST (empty vmcnt queue): the HBM-random long pole. 8 iters/thread.
    {
        const int c4  = tid & 63;
        const int rg0 = tid >> 6;       // 0..7
        const float4* m4 = (const float4*)memory;
        #pragma unroll
        for (int i = 0; i < 8; ++i) {
            int r = i * 8 + rg0;
            int4   id = p_idx[r];
            float4 wv = p_w[r];
            float4 v00 = m4[(size_t)id.x * 64 + c4];
            float4 v01 = m4[(size_t)id.y * 64 + c4];
            float4 v10 = m4[(size_t)id.z * 64 + c4];
            float4 v11 = m4[(size_t)id.w * 64 + c4];
            bf16x4 e;
            e[0] = (__bf16)(wv.x * v00.x + wv.y * v01.x + wv.z * v10.x + wv.w * v11.x);
            e[1] = (__bf16)(wv.x * v00.y + wv.y * v01.y + wv.z * v10.y + wv.w * v11.y);
            e[2] = (__bf16)(wv.x * v00.z + wv.y * v01.z + wv.z * v10.z + wv.w * v11.z);
            e[3] = (__bf16)(wv.x * v00.w + wv.y * v01.w + wv.z * v10.w + wv.w * v11.w);
            *(bf16x4*)&emb_lds[r * APAD + c4 * 4] = e;
        }
    }

    // ---- phase 2.5: W1 B-fragments (this wave's 32 cols) from fp32, in-register cast.
    // frag[ks][nt] lane layout: n = w*32+nt*16+lrow, k = ks*32+quad*8+e.
    // L2-resident (256 KB shared by all blocks); latency drains under the barrier.
    bf16x8 bfrag[8][2];
    {
        const int kbase = quad * 8;
        #pragma unroll
        for (int ks = 0; ks < 8; ++ks) {
            #pragma unroll
            for (int nt = 0; nt < 2; ++nt) {
                const int n = w * 32 + nt * 16 + lrow;
                const float* src = W1 + (ks * 32 + kbase) * NC + n;
                bf16x8 f;
                #pragma unroll
                for (int e = 0; e < 8; ++e)
                    f[e] = (__bf16)src[e * NC];
                bfrag[ks][nt] = f;
            }
        }
    }
    __syncthreads();

    // ---- phase 3: layer-1 MFMA, 64 rows x 32 cols per wave ----
    f32x4 acc[4][2] = {};
    #pragma unroll
    for (int ks = 0; ks < 8; ++ks) {
        bf16x8 a[4];
        #pragma unroll
        for (int mt = 0; mt < 4; ++mt)
            a[mt] = *(const bf16x8*)&emb_lds[(mt * 16 + lrow) * APAD + ks * 32 + quad * 8];
        #pragma unroll
        for (int nt = 0; nt < 2; ++nt)
            #pragma unroll
            for (int mt = 0; mt < 4; ++mt)
                acc[mt][nt] = __builtin_amdgcn_mfma_f32_16x16x32_bf16(a[mt], bfrag[ks][nt], acc[mt][nt], 0, 0, 0);
    }

    // ---- phase 3.5: W2 hi/lo bf16 B-fragments, waves 0-3 only (they run phase 5).
    // 4 KB L1/L2-hot table; loads hide under phase-4 tanh VALU.
    bf16x8 w2hi[8], w2lo[8];
    if (w < 4) {
        const int jj = lrow & 3;
        const float zval = (lrow < 4) ? 1.0f : 0.0f;
        #pragma unroll
        for (int ks = 0; ks < 8; ++ks) {
            bf16x8 h8, l8;
            #pragma unroll
            for (int e = 0; e < 8; ++e) {
                float v = W2[(ks * 32 + quad * 8 + e) * 4 + jj] * zval;
                __bf16 hi = (__bf16)v;
                __bf16 lo = (__bf16)(v - (float)hi);
                h8[e] = hi; l8[e] = lo;
            }
            w2hi[ks] = h8; w2lo[ks] = l8;
        }
    }

    // ---- phase 4: h = fast_tanh(acc + b1) -> h_lds (separate buffer, no pre-barrier) ----
    #pragma unroll
    for (int mt = 0; mt < 4; ++mt) {
        #pragma unroll
        for (int nt = 0; nt < 2; ++nt) {
            const int n = w * 32 + nt * 16 + lrow;
            const float bias = b1_lds[n];
            #pragma unroll
            for (int rg = 0; rg < 4; ++rg) {
                const int row = mt * 16 + quad * 4 + rg;
                h_lds[row * APAD + n] = (__bf16)fast_tanh(acc[mt][nt][rg] + bias);
            }
        }
    }
    __syncthreads();

    // ---- phase 5: layer-2 via MFMA on waves 0-3 (16 rows each); waves 4-7 exit.
    // acc2 layout: row = quad*4+rg, col(j) = lrow.
    if (w < 4) {
        f32x4 acc2 = {};
        #pragma unroll
        for (int ks = 0; ks < 8; ++ks) {
            bf16x8 a = *(const bf16x8*)&h_lds[(w * 16 + lrow) * APAD + ks * 32 + quad * 8];
            acc2 = __builtin_amdgcn_mfma_f32_16x16x32_bf16(a, w2lo[ks], acc2, 0, 0, 0);
            acc2 = __builtin_amdgcn_mfma_f32_16x16x32_bf16(a, w2hi[ks], acc2, 0, 0, 0);
        }
        if (lrow < 4) {
            const int j = lrow;
            #pragma unroll
            for (int rg = 0; rg < 4; ++rg) {
                const int r  = w * 16 + quad * 4 + rg;
                const int s  = r & 7;
                const int qg = blockIdx.x * QPB + (r >> 3);
                float o = S_SCALE * fast_tanh(acc2[rg] + b2v);
                float2 sp2 = spts_lds[r];
                float sp = ((j & 1) == 0) ? sp2.x : sp2.y;
                out[(size_t)qg * 32 + s * 4 + j] = o + sp;
            }
        }
    }
}

extern "C" void kernel_launch(void* const* d_in, const int* in_sizes, int n_in,
                              void* d_out, int out_size, void* d_ws, size_t ws_size,
                              hipStream_t stream) {
    const float* ref_polys  = (const float*)d_in[0];
    const int*   ref_levels = (const int*)d_in[1];
    const float* memory     = (const float*)d_in[2];
    const float* W1         = (const float*)d_in[3];
    const float* b1         = (const float*)d_in[4];
    const float* W2         = (const float*)d_in[5];
    const float* b2         = (const float*)d_in[6];
    float* out = (float*)d_out;
    (void)d_ws; (void)ws_size;

    decoder_kernel<<<dim3(NB * NQ / QPB), dim3(512), 0, stream>>>(
        ref_polys, ref_levels, memory, W1, b1, W2, b2, out);
}